// Round 2
// baseline (406.732 us; speedup 1.0000x reference)
//
#include <hip/hip_runtime.h>
#include <cfloat>
#include <cmath>

#define NROWS 16384
#define DDIM  4096
#define NEXP  64
#define TOPK  8

// ---------------------------------------------------------------------------
// Kernel 1: convert W (64 x 4096 f32) to f64 once. 2 MB, L2-resident.
// ---------------------------------------------------------------------------
__global__ __launch_bounds__(256) void wcvt_kernel(const float* __restrict__ W,
                                                   double* __restrict__ Wd) {
    int t = blockIdx.x * 256 + threadIdx.x;
    Wd[t] = (double)W[t];
}

// ---------------------------------------------------------------------------
// Kernel 2: fp64 gate GEMM partials.
// lane = row (64 rows/wave); each wave covers 32 experts x kchunk.
// x: f32 load + 1 cvt per element, amortized over 32 f64 FMAs.
// W: f64, wave-uniform address -> scalar/broadcast load (SGPR fma operand).
// Block = 4 waves = 2 row-groups x 2 expert-groups (same x rows -> L1 share).
// Partials layout [S][e][row] f64 -> fully coalesced writes and reads.
// ---------------------------------------------------------------------------
__global__ __launch_bounds__(256) void gate_kernel(
    const float*  __restrict__ x,
    const double* __restrict__ Wd,
    double* __restrict__ part,
    int S, int kchunk)
{
    const int lane = threadIdx.x & 63;
    const int w    = threadIdx.x >> 6;                               // 0..3
    const int egrp = __builtin_amdgcn_readfirstlane(w & 1);          // uniform
    const int rloc = __builtin_amdgcn_readfirstlane(w >> 1);         // uniform
    const int rp   = blockIdx.x / S;                                 // 0..127
    const int ks   = blockIdx.x % S;
    const int row  = (rp * 2 + rloc) * 64 + lane;
    const int e0   = egrp * 32;
    const int k0   = ks * kchunk;

    double acc[32];
#pragma unroll
    for (int e = 0; e < 32; ++e) acc[e] = 0.0;

    const float* xr = x + (size_t)row * DDIM + k0;

    for (int kb = 0; kb < kchunk; kb += 8) {
        float4 xa = *reinterpret_cast<const float4*>(xr + kb);
        float4 xb = *reinterpret_cast<const float4*>(xr + kb + 4);
        double xd[8] = {(double)xa.x, (double)xa.y, (double)xa.z, (double)xa.w,
                        (double)xb.x, (double)xb.y, (double)xb.z, (double)xb.w};
#pragma unroll
        for (int e = 0; e < 32; ++e) {
            const double* wp = Wd + (size_t)(e0 + e) * DDIM + k0 + kb;
            double a = acc[e];
#pragma unroll
            for (int j = 0; j < 8; ++j) a = fma(xd[j], wp[j], a);
            acc[e] = a;
        }
    }

#pragma unroll
    for (int e = 0; e < 32; ++e)
        part[((size_t)ks * NEXP + (e0 + e)) * NROWS + row] = acc[e];
}

// ---------------------------------------------------------------------------
// Kernel 3: per-thread-row reduce + top-8 + sparse softmax (all fp64).
// Strict-greater scan keeps lowest index on ties (matches np/jax top_k).
// ---------------------------------------------------------------------------
__global__ __launch_bounds__(256) void topk_kernel(
    const double* __restrict__ part,
    const float*  __restrict__ b,
    float* __restrict__ outp,
    float* __restrict__ outi,
    int S)
{
    const int row = blockIdx.x * 256 + threadIdx.x;

    double lg[64];
#pragma unroll
    for (int e = 0; e < 64; ++e) lg[e] = (double)b[e];
    for (int s = 0; s < S; ++s) {
#pragma unroll
        for (int e = 0; e < 64; ++e)
            lg[e] += part[((size_t)s * NEXP + e) * NROWS + row];
    }

    unsigned long long sel = 0ull;
    double vals[TOPK];
    int    idx[TOPK];
#pragma unroll
    for (int i = 0; i < TOPK; ++i) {
        double m = -DBL_MAX;
        int mi = 0;
#pragma unroll
        for (int e = 0; e < 64; ++e) {
            bool excl = (sel >> e) & 1ull;
            bool gt = (!excl) && (lg[e] > m);
            m  = gt ? lg[e] : m;
            mi = gt ? e  : mi;
        }
        vals[i] = m;
        idx[i]  = mi;
        sel |= (1ull << mi);
    }

    const double m0 = vals[0];
    double ssum = 0.0;
#pragma unroll
    for (int i = 0; i < TOPK; ++i) ssum += exp(vals[i] - m0);
    const double inv = 1.0 / ssum;

#pragma unroll
    for (int e = 0; e < 64; ++e) {
        float p = ((sel >> e) & 1ull) ? (float)(exp(lg[e] - m0) * inv) : 0.0f;
        outp[(size_t)row * NEXP + e] = p;
    }
#pragma unroll
    for (int i = 0; i < TOPK; ++i)
        outi[(size_t)row * TOPK + i] = (float)idx[i];
}

// ---------------------------------------------------------------------------
// Fallback: fused per-thread-row full-K fp64 gate + topk (no partials).
// Used only if workspace is too small for the split path. Slow but correct.
// ---------------------------------------------------------------------------
template <bool USE_WD>
__global__ __launch_bounds__(64) void fallback_kernel(
    const float*  __restrict__ x,
    const float*  __restrict__ W,
    const double* __restrict__ Wd,
    const float*  __restrict__ b,
    float* __restrict__ outp,
    float* __restrict__ outi)
{
    const int row = blockIdx.x * 64 + threadIdx.x;

    double lg[64];
#pragma unroll
    for (int e = 0; e < 64; ++e) lg[e] = (double)b[e];

    const float* xr = x + (size_t)row * DDIM;
    for (int k = 0; k < DDIM; k += 4) {
        float4 xa = *reinterpret_cast<const float4*>(xr + k);
        double xd[4] = {(double)xa.x, (double)xa.y, (double)xa.z, (double)xa.w};
#pragma unroll
        for (int e = 0; e < 64; ++e) {
            double a = lg[e];
            if (USE_WD) {
                const double* wp = Wd + (size_t)e * DDIM + k;
#pragma unroll
                for (int j = 0; j < 4; ++j) a = fma(xd[j], wp[j], a);
            } else {
                const float* wp = W + (size_t)e * DDIM + k;
#pragma unroll
                for (int j = 0; j < 4; ++j) a = fma(xd[j], (double)wp[j], a);
            }
            lg[e] = a;
        }
    }

    unsigned long long sel = 0ull;
    double vals[TOPK];
    int    idx[TOPK];
#pragma unroll
    for (int i = 0; i < TOPK; ++i) {
        double m = -DBL_MAX;
        int mi = 0;
#pragma unroll
        for (int e = 0; e < 64; ++e) {
            bool excl = (sel >> e) & 1ull;
            bool gt = (!excl) && (lg[e] > m);
            m  = gt ? lg[e] : m;
            mi = gt ? e  : mi;
        }
        vals[i] = m;
        idx[i]  = mi;
        sel |= (1ull << mi);
    }
    const double m0 = vals[0];
    double ssum = 0.0;
#pragma unroll
    for (int i = 0; i < TOPK; ++i) ssum += exp(vals[i] - m0);
    const double inv = 1.0 / ssum;
#pragma unroll
    for (int e = 0; e < 64; ++e) {
        float p = ((sel >> e) & 1ull) ? (float)(exp(lg[e] - m0) * inv) : 0.0f;
        outp[(size_t)row * NEXP + e] = p;
    }
#pragma unroll
    for (int i = 0; i < TOPK; ++i)
        outi[(size_t)row * TOPK + i] = (float)idx[i];
}

// ---------------------------------------------------------------------------
extern "C" void kernel_launch(void* const* d_in, const int* in_sizes, int n_in,
                              void* d_out, int out_size, void* d_ws, size_t ws_size,
                              hipStream_t stream) {
    (void)in_sizes; (void)n_in; (void)out_size;
    const float* x = (const float*)d_in[0];
    const float* W = (const float*)d_in[1];
    const float* b = (const float*)d_in[2];

    float* outp = (float*)d_out;
    float* outi = outp + (size_t)NROWS * NEXP;

    const size_t wd_bytes = (size_t)NEXP * DDIM * sizeof(double);   // 2 MB

    int S = 0;
    for (int s = 8; s >= 1; s >>= 1) {
        size_t need = wd_bytes + (size_t)s * NEXP * NROWS * sizeof(double);
        if (ws_size >= need) { S = s; break; }
    }

    if (S > 0) {
        double* Wd   = (double*)d_ws;
        double* part = (double*)((char*)d_ws + wd_bytes);
        wcvt_kernel<<<(NEXP * DDIM) / 256, 256, 0, stream>>>(W, Wd);
        gate_kernel<<<128 * S, 256, 0, stream>>>(x, Wd, part, S, DDIM / S);
        topk_kernel<<<NROWS / 256, 256, 0, stream>>>(part, b, outp, outi, S);
    } else if (ws_size >= wd_bytes) {
        double* Wd = (double*)d_ws;
        wcvt_kernel<<<(NEXP * DDIM) / 256, 256, 0, stream>>>(W, Wd);
        fallback_kernel<true><<<NROWS / 64, 64, 0, stream>>>(x, nullptr, Wd, b, outp, outi);
    } else {
        fallback_kernel<false><<<NROWS / 64, 64, 0, stream>>>(x, W, nullptr, b, outp, outi);
    }
}